// Round 4
// baseline (239.062 us; speedup 1.0000x reference)
//
#include <hip/hip_runtime.h>

typedef short bf16x8 __attribute__((ext_vector_type(8)));
typedef float f32x4 __attribute__((ext_vector_type(4)));

#define MFMA16(a, b, c) __builtin_amdgcn_mfma_f32_16x16x32_bf16((a), (b), (c), 0, 0, 0)

__device__ __forceinline__ unsigned short f2bf(float f) {
    union { float f; unsigned u; } v; v.f = f;
    unsigned r = v.u + 0x7FFFu + ((v.u >> 16) & 1u);
    return (unsigned short)(r >> 16);
}
__device__ __forceinline__ float bf2f(unsigned short s) {
    union { unsigned u; float f; } v; v.u = (unsigned)s << 16;
    return v.f;
}

// ---------------- prep: fp32 -> bf16 bulk convert ----------------
__global__ __launch_bounds__(256) void k_cvt(const float* __restrict__ in,
                                             unsigned short* __restrict__ out, int n4) {
    int i = blockIdx.x * 256 + threadIdx.x;
    if (i < n4) {
        float4 v = reinterpret_cast<const float4*>(in)[i];
        ushort4 o;
        o.x = f2bf(v.x); o.y = f2bf(v.y); o.z = f2bf(v.z); o.w = f2bf(v.w);
        reinterpret_cast<ushort4*>(out)[i] = o;
    }
}

// ---------------- prep: transpose fp32 [R][C] -> bf16 [C][R] ----------------
__global__ __launch_bounds__(256) void k_tr(const float* __restrict__ in,
                                            unsigned short* __restrict__ out, int R, int C) {
    __shared__ float t[64][65];
    int c0 = blockIdx.x * 64, r0 = blockIdx.y * 64;
    int lc = threadIdx.x & 63, lr4 = threadIdx.x >> 6;  // 64 x 4
#pragma unroll
    for (int j = 0; j < 16; ++j) {
        int r = lr4 + j * 4;
        t[r][lc] = in[(size_t)(r0 + r) * C + c0 + lc];
    }
    __syncthreads();
#pragma unroll
    for (int j = 0; j < 16; ++j) {
        int c = lr4 + j * 4;
        out[(size_t)(c0 + c) * R + r0 + lc] = f2bf(t[lc][c]);
    }
}

// ---------------- shared GEMM mainloop: C128x128 = A[M,512] @ Bt[N,512]^T ----------------
__device__ __forceinline__ void gemm_main_512(const unsigned short* __restrict__ A,
                                              const unsigned short* __restrict__ Bt,
                                              int m0, int n0,
                                              unsigned short* AL, unsigned short* BL,
                                              f32x4 acc[4][4]) {
    const int tid = threadIdx.x;
    const int lane = tid & 63, wid = tid >> 6;
    const int wr = wid >> 1, wc = wid & 1;
    const int lg = lane >> 4, lr = lane & 15;

    for (int k0 = 0; k0 < 512; k0 += 32) {
#pragma unroll
        for (int i = 0; i < 2; ++i) {
            int idx = tid + i * 256;
            int row = idx >> 2;
            int c8 = (idx & 3) * 8;
            *reinterpret_cast<bf16x8*>(&AL[row * 40 + c8]) =
                *reinterpret_cast<const bf16x8*>(&A[(size_t)(m0 + row) * 512 + k0 + c8]);
            *reinterpret_cast<bf16x8*>(&BL[row * 40 + c8]) =
                *reinterpret_cast<const bf16x8*>(&Bt[(size_t)(n0 + row) * 512 + k0 + c8]);
        }
        __syncthreads();
        bf16x8 af[4], bfr[4];
#pragma unroll
        for (int rt = 0; rt < 4; ++rt)
            af[rt] = *reinterpret_cast<const bf16x8*>(&AL[(wr * 64 + rt * 16 + lr) * 40 + lg * 8]);
#pragma unroll
        for (int ct = 0; ct < 4; ++ct)
            bfr[ct] = *reinterpret_cast<const bf16x8*>(&BL[(wc * 64 + ct * 16 + lr) * 40 + lg * 8]);
#pragma unroll
        for (int rt = 0; rt < 4; ++rt)
#pragma unroll
            for (int ct = 0; ct < 4; ++ct)
                acc[rt][ct] = MFMA16(af[rt], bfr[ct], acc[rt][ct]);
        __syncthreads();
    }
}

// ---------------- QKV GEMM: X[8192,512] @ Wt[1536,512]^T ----------------
// Q pre-scaled by 0.125*log2(e) -> [b,h,l,d]; K -> [b,h,l,d];
// V -> TRANSPOSED [b,h,d,l] (packed ushort4 stores: j indexes contiguous l).
__global__ __launch_bounds__(256) void k_gemm_qkv(const unsigned short* __restrict__ X,
                                                  const unsigned short* __restrict__ Wt,
                                                  unsigned short* __restrict__ Qb,
                                                  unsigned short* __restrict__ Kb,
                                                  unsigned short* __restrict__ VbT) {
    __shared__ __align__(16) unsigned short AL[128 * 40];
    __shared__ __align__(16) unsigned short BL[128 * 40];
    f32x4 acc[4][4];
#pragma unroll
    for (int i = 0; i < 4; ++i)
#pragma unroll
        for (int j = 0; j < 4; ++j) acc[i][j] = (f32x4){0.f, 0.f, 0.f, 0.f};

    int m0 = blockIdx.x * 128, n0 = blockIdx.y * 128;
    gemm_main_512(X, Wt, m0, n0, AL, BL, acc);

    const int tid = threadIdx.x;
    const int lane = tid & 63, wid = tid >> 6;
    const int wr = wid >> 1, wc = wid & 1;
    const int lg = lane >> 4, lr = lane & 15;
    const int which = n0 >> 9;  // block-uniform: 128-col tile within one 512 third
#pragma unroll
    for (int rt = 0; rt < 4; ++rt) {
#pragma unroll
        for (int ct = 0; ct < 4; ++ct) {
            int col = n0 + wc * 64 + ct * 16 + lr;
            int inner = col & 511;
            int h = inner >> 6, d = inner & 63;
            int row0 = m0 + wr * 64 + rt * 16 + lg * 4;
            int b = row0 >> 12, l0 = row0 & 4095;
            if (which == 0) {
#pragma unroll
                for (int j = 0; j < 4; ++j)
                    Qb[(((size_t)(b * 8 + h)) * 4096 + l0 + j) * 64 + d] =
                        f2bf(acc[rt][ct][j] * 0.18033688f);
            } else if (which == 1) {
#pragma unroll
                for (int j = 0; j < 4; ++j)
                    Kb[(((size_t)(b * 8 + h)) * 4096 + l0 + j) * 64 + d] = f2bf(acc[rt][ct][j]);
            } else {
                ushort4 o;
                o.x = f2bf(acc[rt][ct][0]); o.y = f2bf(acc[rt][ct][1]);
                o.z = f2bf(acc[rt][ct][2]); o.w = f2bf(acc[rt][ct][3]);
                *reinterpret_cast<ushort4*>(
                    &VbT[(((size_t)(b * 8 + h)) * 64 + d) * 4096 + l0]) = o;
            }
        }
    }
}

// ---------------- OUT GEMM: An[8192,512] @ Wot[512,512]^T + b -> out fp32 ----------------
__global__ __launch_bounds__(256) void k_gemm_out(const unsigned short* __restrict__ An,
                                                  const unsigned short* __restrict__ Wot,
                                                  const float* __restrict__ bout,
                                                  float* __restrict__ out) {
    __shared__ __align__(16) unsigned short AL[128 * 40];
    __shared__ __align__(16) unsigned short BL[128 * 40];
    f32x4 acc[4][4];
#pragma unroll
    for (int i = 0; i < 4; ++i)
#pragma unroll
        for (int j = 0; j < 4; ++j) acc[i][j] = (f32x4){0.f, 0.f, 0.f, 0.f};

    int m0 = blockIdx.x * 128, n0 = blockIdx.y * 128;
    gemm_main_512(An, Wot, m0, n0, AL, BL, acc);

    const int tid = threadIdx.x;
    const int lane = tid & 63, wid = tid >> 6;
    const int wr = wid >> 1, wc = wid & 1;
    const int lg = lane >> 4, lr = lane & 15;
#pragma unroll
    for (int rt = 0; rt < 4; ++rt) {
#pragma unroll
        for (int ct = 0; ct < 4; ++ct) {
            int col = n0 + wc * 64 + ct * 16 + lr;
            float bv = bout[col];
#pragma unroll
            for (int j = 0; j < 4; ++j) {
                int row = m0 + wr * 64 + rt * 16 + lg * 4 + j;
                out[(size_t)row * 512 + col] = acc[rt][ct][j] + bv;
            }
        }
    }
}

// ---------------- flash attention, KV split 2-ways across blocks ----------------
// blockIdx.z = KV half. No-max softmax => partial (O, l) combine by ADDITION.
// Writes unnormalized O-half (bf16, An layout) + rowsum l (fp32).
__global__ __launch_bounds__(256) void k_attn(const unsigned short* __restrict__ Q,
                                              const unsigned short* __restrict__ K,
                                              const unsigned short* __restrict__ VT,
                                              unsigned short* __restrict__ Op0,
                                              unsigned short* __restrict__ Op1,
                                              float* __restrict__ Lp) {
    __shared__ __align__(16) unsigned short KL[64 * 72];
    __shared__ __align__(16) unsigned short VTl[64 * 72];
    __shared__ __align__(16) unsigned short PL[4][32 * 72];

    const int qt = blockIdx.x;   // 0..31
    const int bh = blockIdx.y;   // 0..15
    const int hh = blockIdx.z;   // 0..1  KV half
    const size_t base = (size_t)bh * 4096 * 64;  // K: [l][64]; VT: [64][4096]
    const int kvbase = hh * 2048;
    const int tid = threadIdx.x, lane = tid & 63, wid = tid >> 6;
    const int lg = lane >> 4, lr = lane & 15;
    const int q0 = qt * 128 + wid * 32;

    bf16x8 qf[2][2];
#pragma unroll
    for (int rt = 0; rt < 2; ++rt)
#pragma unroll
        for (int kt = 0; kt < 2; ++kt)
            qf[rt][kt] = *reinterpret_cast<const bf16x8*>(
                &Q[base + (size_t)(q0 + rt * 16 + lr) * 64 + kt * 32 + lg * 8]);

    f32x4 oacc[2][4];
    f32x4 sacc[2];
#pragma unroll
    for (int rt = 0; rt < 2; ++rt) {
        sacc[rt] = (f32x4){0.f, 0.f, 0.f, 0.f};
#pragma unroll
        for (int dt = 0; dt < 4; ++dt) oacc[rt][dt] = (f32x4){0.f, 0.f, 0.f, 0.f};
    }

    bf16x8 ones;
#pragma unroll
    for (int j = 0; j < 8; ++j) ones[j] = (short)0x3F80;  // bf16 1.0

    const int r0 = tid >> 3, c0 = (tid & 7) * 8;

    // prologue: stage KV tile 0 of this half
    bf16x8 kreg[2], vreg[2];
#pragma unroll
    for (int i = 0; i < 2; ++i) {
        kreg[i] = *reinterpret_cast<const bf16x8*>(
            &K[base + (size_t)(kvbase + r0 + i * 32) * 64 + c0]);
        vreg[i] = *reinterpret_cast<const bf16x8*>(
            &VT[base + (size_t)(r0 + i * 32) * 4096 + kvbase + c0]);
    }
#pragma unroll
    for (int i = 0; i < 2; ++i) {
        *reinterpret_cast<bf16x8*>(&KL[(r0 + i * 32) * 72 + c0]) = kreg[i];
        *reinterpret_cast<bf16x8*>(&VTl[(r0 + i * 32) * 72 + c0]) = vreg[i];
    }
    __syncthreads();

    for (int kv = 0; kv < 32; ++kv) {
        const int kv0n = kvbase + kv * 64 + 64;
        if (kv < 31) {
#pragma unroll
            for (int i = 0; i < 2; ++i) {
                kreg[i] = *reinterpret_cast<const bf16x8*>(
                    &K[base + (size_t)(kv0n + r0 + i * 32) * 64 + c0]);
                vreg[i] = *reinterpret_cast<const bf16x8*>(
                    &VT[base + (size_t)(r0 + i * 32) * 4096 + kv0n + c0]);
            }
        }

        // S = Qs @ K^T
        f32x4 s[2][4];
#pragma unroll
        for (int rt = 0; rt < 2; ++rt)
#pragma unroll
            for (int ct = 0; ct < 4; ++ct) s[rt][ct] = (f32x4){0.f, 0.f, 0.f, 0.f};
        __builtin_amdgcn_s_setprio(1);
#pragma unroll
        for (int kt = 0; kt < 2; ++kt) {
#pragma unroll
            for (int ct = 0; ct < 4; ++ct) {
                bf16x8 kf = *reinterpret_cast<const bf16x8*>(
                    &KL[(ct * 16 + lr) * 72 + kt * 32 + lg * 8]);
#pragma unroll
                for (int rt = 0; rt < 2; ++rt)
                    s[rt][ct] = MFMA16(qf[rt][kt], kf, s[rt][ct]);
            }
        }
        __builtin_amdgcn_s_setprio(0);

        // P = 2^S -> per-wave LDS (A-fragment relayout)
#pragma unroll
        for (int rt = 0; rt < 2; ++rt)
#pragma unroll
            for (int ct = 0; ct < 4; ++ct)
#pragma unroll
                for (int j = 0; j < 4; ++j)
                    PL[wid][(rt * 16 + lg * 4 + j) * 72 + ct * 16 + lr] =
                        f2bf(__builtin_amdgcn_exp2f(s[rt][ct][j]));

        // O += P @ V ; l += P @ ones
        __builtin_amdgcn_s_setprio(1);
#pragma unroll
        for (int kt = 0; kt < 2; ++kt) {
            bf16x8 pf[2];
#pragma unroll
            for (int rt = 0; rt < 2; ++rt)
                pf[rt] = *reinterpret_cast<const bf16x8*>(
                    &PL[wid][(rt * 16 + lr) * 72 + kt * 32 + lg * 8]);
#pragma unroll
            for (int dt = 0; dt < 4; ++dt) {
                bf16x8 vf = *reinterpret_cast<const bf16x8*>(
                    &VTl[(dt * 16 + lr) * 72 + kt * 32 + lg * 8]);
#pragma unroll
                for (int rt = 0; rt < 2; ++rt)
                    oacc[rt][dt] = MFMA16(pf[rt], vf, oacc[rt][dt]);
            }
#pragma unroll
            for (int rt = 0; rt < 2; ++rt)
                sacc[rt] = MFMA16(pf[rt], ones, sacc[rt]);
        }
        __builtin_amdgcn_s_setprio(0);

        __syncthreads();
        if (kv < 31) {
#pragma unroll
            for (int i = 0; i < 2; ++i) {
                *reinterpret_cast<bf16x8*>(&KL[(r0 + i * 32) * 72 + c0]) = kreg[i];
                *reinterpret_cast<bf16x8*>(&VTl[(r0 + i * 32) * 72 + c0]) = vreg[i];
            }
        }
        __syncthreads();
    }

    // write unnormalized O-half (bf16, An layout [b, l, h*64+d]) + rowsums
    unsigned short* Op = hh ? Op1 : Op0;
    const int b = bh >> 3, h = bh & 7;
#pragma unroll
    for (int rt = 0; rt < 2; ++rt) {
#pragma unroll
        for (int j = 0; j < 4; ++j) {
            int row = q0 + rt * 16 + lg * 4 + j;
#pragma unroll
            for (int dt = 0; dt < 4; ++dt) {
                int d = dt * 16 + lr;
                Op[((size_t)b * 4096 + row) * 512 + h * 64 + d] = f2bf(oacc[rt][dt][j]);
            }
            if (lr == 0)
                Lp[((size_t)(hh * 16 + bh)) * 4096 + row] = sacc[rt][j];
        }
    }
}

// ---------------- combine halves: An = (O0+O1)/(l0+l1) ----------------
__global__ __launch_bounds__(256) void k_reduce(const unsigned short* __restrict__ O0,
                                                const unsigned short* __restrict__ O1,
                                                const float* __restrict__ Lp,
                                                unsigned short* __restrict__ An) {
    int i4 = blockIdx.x * 256 + threadIdx.x;   // 1,048,576 total (x4 elems)
    int e = i4 * 4;
    int r = e >> 9;                 // b*4096 + l
    int c = e & 511, h = c >> 6;
    int b = r >> 12, l = r & 4095;
    int lidx = (b * 8 + h) * 4096 + l;
    float inv = 1.f / (Lp[lidx] + Lp[16 * 4096 + lidx]);
    ushort4 a = *reinterpret_cast<const ushort4*>(&O0[e]);
    ushort4 bq = *reinterpret_cast<const ushort4*>(&O1[e]);
    ushort4 o;
    o.x = f2bf((bf2f(a.x) + bf2f(bq.x)) * inv);
    o.y = f2bf((bf2f(a.y) + bf2f(bq.y)) * inv);
    o.z = f2bf((bf2f(a.z) + bf2f(bq.z)) * inv);
    o.w = f2bf((bf2f(a.w) + bf2f(bq.w)) * inv);
    *reinterpret_cast<ushort4*>(&An[e]) = o;
}

extern "C" void kernel_launch(void* const* d_in, const int* in_sizes, int n_in,
                              void* d_out, int out_size, void* d_ws, size_t ws_size,
                              hipStream_t stream) {
    const float* x    = (const float*)d_in[0];   // [2,4096,512]
    const float* Wqkv = (const float*)d_in[1];   // [512,1536]
    const float* Wout = (const float*)d_in[2];   // [512,512]
    const float* bout = (const float*)d_in[3];   // [512]
    float* out = (float*)d_out;                  // [2,4096,512] fp32

    char* ws = (char*)d_ws;
    // region reuse: Xbf is dead after k_gemm_qkv -> becomes Op0.
    //               Wqkt is dead after k_gemm_qkv -> becomes Lp.
    //               An region doubles as Op1 (k_reduce combines in place).
    unsigned short* Xbf  = (unsigned short*)(ws);                         // 8,388,608 B
    unsigned short* Wqkt = (unsigned short*)(ws + 8388608);               // 1,572,864 B
    unsigned short* Wot  = (unsigned short*)(ws + 8388608 + 1572864);     //   524,288 B
    unsigned short* Qb   = (unsigned short*)(ws + 10485760);              // 8,388,608 B
    unsigned short* Kb   = (unsigned short*)(ws + 18874368);              // 8,388,608 B
    unsigned short* VbT  = (unsigned short*)(ws + 27262976);              // 8,388,608 B [bh][d][l]
    unsigned short* An   = (unsigned short*)(ws + 35651584);              // 8,388,608 B
    unsigned short* Op0  = Xbf;                                           // reuse
    unsigned short* Op1  = An;                                            // reuse (in-place reduce)
    float*          Lp   = (float*)(ws + 8388608);                        //   524,288 B (in Wqkt)

    k_cvt<<<4096, 256, 0, stream>>>(x, Xbf, 4194304 / 4);
    k_tr<<<dim3(24, 8), 256, 0, stream>>>(Wqkv, Wqkt, 512, 1536);
    k_tr<<<dim3(8, 8), 256, 0, stream>>>(Wout, Wot, 512, 512);
    k_gemm_qkv<<<dim3(64, 12), 256, 0, stream>>>(Xbf, Wqkt, Qb, Kb, VbT);
    k_attn<<<dim3(32, 16, 2), 256, 0, stream>>>(Qb, Kb, VbT, Op0, Op1, Lp);
    k_reduce<<<4096, 256, 0, stream>>>(Op0, Op1, Lp, An);
    k_gemm_out<<<dim3(64, 4), 256, 0, stream>>>(An, Wot, bout, out);
}